// Round 12
// baseline (185.056 us; speedup 1.0000x reference)
//
#include <hip/hip_runtime.h>
#include <stdint.h>

using f16 = _Float16;

typedef _Float16 f16x8 __attribute__((ext_vector_type(8)));
typedef _Float16 f16x4 __attribute__((ext_vector_type(4)));
typedef float f32x4 __attribute__((ext_vector_type(4)));

#define LOG2E 1.44269504088896340736f

__device__ __forceinline__ f16 f2h(float f) { return (f16)f; }  // RNE

#if __has_builtin(__builtin_amdgcn_exp2f)
__device__ __forceinline__ float fexp2(float x) { return __builtin_amdgcn_exp2f(x); }
#else
__device__ __forceinline__ float fexp2(float x) { return exp2f(x); }
#endif

typedef __attribute__((address_space(1))) const uint32_t gu32;
typedef __attribute__((address_space(3))) uint32_t lu32;

__device__ __forceinline__ void dma16(const void* g, void* l) {
  // global->LDS DMA, 16 B/lane. Global source is PER-LANE; LDS dest is
  // wave-uniform base + lane*16 auto-stride.
  __builtin_amdgcn_global_load_lds((gu32*)g, (lu32*)l, 16, 0, 0);
}

__device__ __forceinline__ f16x8 cvt8(const float* p) {
  const float4 a = *(const float4*)p;
  const float4 b = *(const float4*)(p + 4);
  f16x8 r;
  r[0] = (f16)a.x; r[1] = (f16)a.y; r[2] = (f16)a.z; r[3] = (f16)a.w;
  r[4] = (f16)b.x; r[5] = (f16)b.y; r[6] = (f16)b.z; r[7] = (f16)b.w;
  return r;
}

// B=4, C=64, N=4096.  Global in/out FP32; internal tensor-core path FP16.
// ws layout (bytes):
//   0     qa  f16 [4][4096][64]      (2 MB)  q*log2e, position-major
//   2 MB  ka2 f16 [4][8][4096][8]    (2 MB)  K channel-chunked: [b][c8][key][8c]
//   4 MB  va3 f16 [4][512][64][8]    (2 MB)  V key-chunked:     [b][k8][c][8k]
//   6 MB  y0  f32 [4][64][4096]      (4 MB)  gamma*attn_out, pre-BN
//   10 MB stats: gs1[64] | gs2[64]   (zeroed by pre block 0)

// ---------------------------------------------------------------------------
// pre v3 (r11 verbatim, plain ka2): 1024 blocks x 256 thr, 16-pos tiles.
// ---------------------------------------------------------------------------
__global__ __launch_bounds__(256, 2) void pam_pre(
    const float* __restrict__ x, const float* __restrict__ qw,
    const float* __restrict__ kw, const float* __restrict__ vw,
    const float* __restrict__ vb,
    f16* __restrict__ qa, f16* __restrict__ ka2, f16* __restrict__ va3,
    float* __restrict__ gz)
{
  __shared__ alignas(16) f16 xt[16 * 72];   // xt[n][c] f16, row stride 72
  const int tid = threadIdx.x;
  const int b = blockIdx.x >> 8;
  const int n0 = (blockIdx.x & 255) << 4;
  const int lane = tid & 63;
  const int wv = tid >> 6;
  const int quad = lane >> 4, l15 = lane & 15;

  if (blockIdx.x == 0 && tid < 128) gz[tid] = 0.f;   // gs1|gs2 zero-init

  // stage x[b][c][n0:+16] (fp32) transposed into xt[n][c] (f16)
  {
    const int c = tid >> 2;
    const int j0 = (tid & 3) << 2;
    const float4 v0 = *(const float4*)(x + ((size_t)(b * 64 + c) << 12) + n0 + j0);
    xt[(j0 + 0) * 72 + c] = f2h(v0.x);
    xt[(j0 + 1) * 72 + c] = f2h(v0.y);
    xt[(j0 + 2) * 72 + c] = f2h(v0.z);
    xt[(j0 + 3) * 72 + c] = f2h(v0.w);
  }
  __syncthreads();

  // conv over channel axis (SAME, zero pad): 128 threads, 8 channels each
  if (tid < 128) {
    const float qw0 = qw[0], qw1 = qw[1], qw2 = qw[2];
    const float kw0 = kw[0], kw1 = kw[1], kw2 = kw[2];
    const int n = tid >> 3;            // 0..15
    const int c8 = tid & 7;            // 0..7
    const f16x8 v0 = *(const f16x8*)&xt[n * 72 + c8 * 8];
    const float lm = (c8 > 0) ? (float)xt[n * 72 + c8 * 8 - 1] : 0.f;
    const float rp = (c8 < 7) ? (float)xt[n * 72 + c8 * 8 + 8] : 0.f;
    f16x8 qv8, kv8;
#pragma unroll
    for (int j = 0; j < 8; ++j) {
      const float xm = (j == 0) ? lm : (float)v0[j - 1];
      const float x0 = (float)v0[j];
      const float xp = (j == 7) ? rp : (float)v0[j + 1];
      qv8[j] = f2h((qw0 * xm + qw1 * x0 + qw2 * xp) * LOG2E);  // log2-domain
      kv8[j] = f2h(kw0 * xm + kw1 * x0 + kw2 * xp);
    }
    const int nn = n0 + n;
    *(f16x8*)(qa + ((size_t)((b << 12) + nn) << 6) + c8 * 8) = qv8;
    *(f16x8*)(ka2 + (((size_t)(b * 8 + c8)) << 15) + (nn << 3)) = kv8;
  }

  // v^T[n][co] via mfma; wave wv -> co columns [16wv,+16)
  {
    const f16x8 a0 = *(const f16x8*)&xt[l15 * 72 + quad * 8];
    const f16x8 a1 = *(const f16x8*)&xt[l15 * 72 + quad * 8 + 32];
    const int co = wv * 16 + l15;
    const f16x8 b0 = cvt8(vw + co * 64 + quad * 8);
    const f16x8 b1 = cvt8(vw + co * 64 + quad * 8 + 32);
    f32x4 z = {0.f, 0.f, 0.f, 0.f};
    z = __builtin_amdgcn_mfma_f32_16x16x32_f16(a0, b0, z, 0, 0, 0);
    z = __builtin_amdgcn_mfma_f32_16x16x32_f16(a1, b1, z, 0, 0, 0);
    const float vbv = vb[co];
    f16x4 pv;
#pragma unroll
    for (int r = 0; r < 4; ++r) pv[r] = f2h(z[r] + vbv);
    const int nb = n0 + quad * 4;      // 4 consecutive n per thread
    *(f16x4*)(va3 + (((size_t)(b * 512 + (nb >> 3))) << 9)
              + (co << 3) + (nb & 7)) = pv;
  }
}

// ---------------------------------------------------------------------------
// attention v26: the TLP round.  Diagnosis across r7/r10/r11: both pipes
// <30% busy, HBM idle, Occupancy 34% -- latency-bound at 4 waves/SIMD.
// Fix: grid 1024 (4 blocks/CU), 512 thr, 16-query tiles, 8-way key split
// -> 32 waves/CU = 8 waves/SIMD, double every prior structure.
//  - each wave owns 16 DISJOINT keys/tile (no duplication), staged
//    wave-private (r11's zero-barrier scheme): 2 dma16/iter into a private
//    2x2KB LDS ring; sync = per-wave counted vmcnt only; no s_barrier.
//  - 16-key granularity makes all layouts IDENTITY: 16x16 C-layout
//    (row=quad*4+r) == 16x16x16 A/B k-layout (k=quad*4+j).  No permutation,
//    plain ka2, linear conflict-free LDS reads (r11 measured 0 conflicts).
//  - QK^T: 2x 16x16x32 chained.  PV: 4x 16x16x16 (V f16x4 from global,
//    issued at iter top).  Softmax: 4 regs, lane-local, defer-max THR=8.
//  - LDS ~38 KB; __launch_bounds__(512,8) caps VGPR at 64 (est ~60).
// ---------------------------------------------------------------------------
__global__ __launch_bounds__(512, 8) void pam_attn(
    const f16* __restrict__ qa, const f16* __restrict__ ka2,
    const f16* __restrict__ va3, const float* __restrict__ gam,
    float* __restrict__ y0, float* __restrict__ gs1, float* __restrict__ gs2)
{
  __shared__ alignas(16) f16 kbuf[8][2048];   // 4 KB per wave, 2x2KB buffers
  __shared__ float ldsO[16 * 65];             // [q][c], pad 65
  __shared__ float ldsM[8][16], ldsL[8][16], ldsMg[16], ldsInv[16];

  const int tid = threadIdx.x;
  const int wv = tid >> 6, lane = tid & 63;
  const int quad = lane >> 4, l15 = lane & 15;
  const int ks = wv;                        // key-slice 0..7
  const int b = blockIdx.x & 3;
  const int qb = blockIdx.x >> 2;           // 0..255
  const int qb0 = qb << 4;                  // 16-query base
  const int phase = qb & 31;                // L2-spread rotation (32 tiles)

  for (int i = tid; i < 16 * 65; i += 512) ldsO[i] = 0.f;
  __syncthreads();                          // ldsO zeroed before merge use

  const int bn = b << 12;
  // Q fragments (B-operand: col=l15=q, k=quad*8+j over channels)
  f16x8 bq0, bq1;
  {
    const int q = qb0 + l15;
    const f16* qp = qa + ((size_t)(bn + q) << 6) + quad * 8;
    bq0 = *(const f16x8*)qp;
    bq1 = *(const f16x8*)(qp + 32);
  }

  // per-lane K DMA sources: dma j covers c8 = j*4 + (lane>>4),
  // key = tile_base + ks*16 + (lane&15).  LDS layout [4 c8][16 key][8c]/KB.
  const f16* kgs0 = ka2 + (((size_t)(b * 8 + (lane >> 4))) << 15)
                  + ((ks * 16 + (lane & 15)) << 3);
  const f16* kgs1 = kgs0 + (4 << 15);       // c8 + 4
  f16* const kwv = kbuf[wv];                // this wave's private 4 KB

  // V per-lane base: va3[b][k8 = 16g + ks*2 + (quad>>1)][c][(quad&1)*4 + j]
  const f16* vgp = va3 + ((size_t)b << 18) + (((ks << 1) + (quad >> 1)) << 9)
                 + (l15 << 3) + ((quad & 1) << 2);

  f32x4 o[4] = {};                 // O^T: col=l15=q, row c = ct*16+quad*4+r
  float m = -1e30f, lp = 0.f;

  // linear K read offset: [c8=quad][key=l15] (+512 f16 -> c8 4..7)
  const int koff = (quad << 7) + (l15 << 3);

  // prologue: stage tile 'phase' into buffer 0 (2 dma16 outstanding)
  dma16(kgs0 + ((size_t)phase << 10), kwv);
  dma16(kgs1 + ((size_t)phase << 10), kwv + 512);

#pragma unroll 1
  for (int kt = 0; kt < 32; ++kt) {
    const int cur = kt & 1;
    const int gcur = (kt + phase) & 31;

    // V fragments for THIS tile (A-frag f16x4, c = ct*16+l15, k = quad*4+j)
    const f16* vt = vgp + ((size_t)gcur << 13);
    const f16x4 av0 = *(const f16x4*)(vt);
    const f16x4 av1 = *(const f16x4*)(vt + 128);
    const f16x4 av2 = *(const f16x4*)(vt + 256);
    const f16x4 av3 = *(const f16x4*)(vt + 384);
    __builtin_amdgcn_sched_barrier(0);

    // retire DMA(t) (oldest 2 of 6 outstanding); V(t) stays in flight
    asm volatile("s_waitcnt vmcnt(4)" ::: "memory");
    __builtin_amdgcn_sched_barrier(0);

    // linear K reads from this wave's private buffer
    const f16* kc = kwv + (cur << 10);
    const f16x8 ak0 = *(const f16x8*)(kc + koff);
    const f16x8 ak1 = *(const f16x8*)(kc + 512 + koff);

    // S^T[16 key][16 q], contraction over 64 channels
    f32x4 z0;
    {
      f32x4 z = {0.f, 0.f, 0.f, 0.f};
      z = __builtin_amdgcn_mfma_f32_16x16x32_f16(ak0, bq0, z, 0, 0, 0);
      z0 = __builtin_amdgcn_mfma_f32_16x16x32_f16(ak1, bq1, z, 0, 0, 0);
    }

    // prefetch K(t+1) into the other private buffer (self-paced)
    if (kt < 31) {
      const size_t off = (size_t)((kt + 1 + phase) & 31) << 10;
      f16* dst = kwv + ((cur ^ 1) << 10);
      dma16(kgs0 + off, dst);
      dma16(kgs1 + off, dst + 512);
    }

    // online softmax: lane holds keys quad*4+{0..3} for query q=l15
    float tmax = fmaxf(fmaxf(z0[0], z0[1]), fmaxf(z0[2], z0[3]));
    tmax = fmaxf(tmax, __shfl_xor(tmax, 16, 64));
    tmax = fmaxf(tmax, __shfl_xor(tmax, 32, 64));
    const bool need = !__all(tmax <= m + 8.f);    // defer-max, THR=8
    const float mn = need ? fmaxf(m, tmax) : m;

    const float p0 = fexp2(z0[0] - mn);
    const float p1 = fexp2(z0[1] - mn);
    const float p2 = fexp2(z0[2] - mn);
    const float p3 = fexp2(z0[3] - mn);
    const float ts = (p0 + p1) + (p2 + p3);

    f16x4 pa;   // P B-frag: k = quad*4+j == S^T reg order (identity)
    pa[0] = f2h(p0); pa[1] = f2h(p1); pa[2] = f2h(p2); pa[3] = f2h(p3);

    if (need) {
      const float al = fexp2(m - mn);   // lane-local (q in column)
      lp = lp * al + ts;
      m = mn;
#pragma unroll
      for (int ct = 0; ct < 4; ++ct)
        for (int r = 0; r < 4; ++r) o[ct][r] *= al;
    } else {
      lp += ts;
    }

    // O^T += V * P^T : 16x16x16 per 16-channel tile (V from registers;
    // compiler's V-wait retires V(t) in-order, DMA(t+1) stays in flight)
    o[0] = __builtin_amdgcn_mfma_f32_16x16x16f16(av0, pa, o[0], 0, 0, 0);
    o[1] = __builtin_amdgcn_mfma_f32_16x16x16f16(av1, pa, o[1], 0, 0, 0);
    o[2] = __builtin_amdgcn_mfma_f32_16x16x16f16(av2, pa, o[2], 0, 0, 0);
    o[3] = __builtin_amdgcn_mfma_f32_16x16x16f16(av3, pa, o[3], 0, 0, 0);
  }

  // drain trailing VMEM before cross-wave LDS phases
  asm volatile("s_waitcnt vmcnt(0)" ::: "memory");

  // publish per-wave online state (m quad-uniform; lp reduced across quads)
  {
    float v = lp;
    v += __shfl_xor(v, 16, 64);
    v += __shfl_xor(v, 32, 64);
    if (quad == 0) {
      ldsM[ks][l15] = m;
      ldsL[ks][l15] = v;
    }
  }
  __syncthreads();

  // per-query global max + denom (8 key-slices)
  if (tid < 16) {
    float M = ldsM[0][tid];
#pragma unroll
    for (int k = 1; k < 8; ++k) M = fmaxf(M, ldsM[k][tid]);
    float lt = 0.f;
#pragma unroll
    for (int k = 0; k < 8; ++k) lt += ldsL[k][tid] * fexp2(ldsM[k][tid] - M);
    ldsMg[tid] = M;
    ldsInv[tid] = 1.f / lt;
  }
  __syncthreads();

  // m-aware merge of partial O^T across the 8 key-split waves (sc lane-local)
  {
    const int q = l15;
    const float sc = fexp2(m - ldsMg[q]);
#pragma unroll
    for (int ct = 0; ct < 4; ++ct)
      for (int r = 0; r < 4; ++r)
        atomicAdd(&ldsO[q * 65 + ct * 16 + quad * 4 + r], o[ct][r] * sc);
  }
  __syncthreads();

  // epilogue: y0[b][c][n] = gamma * O / l ; BN partial sums (2 elems/thread)
  const float g = gam[0];
  {
    const int c = tid >> 3;              // 0..63
    const int q0 = (tid & 7) << 1;       // 0,2,..,14
    float2 v2;
    float s1 = 0.f, s2 = 0.f;
    {
      const float v0 = g * ldsO[(q0 + 0) * 65 + c] * ldsInv[q0 + 0];
      const float v1 = g * ldsO[(q0 + 1) * 65 + c] * ldsInv[q0 + 1];
      v2.x = v0; v2.y = v1;
      s1 = v0 + v1; s2 = v0 * v0 + v1 * v1;
    }
    *(float2*)(y0 + ((size_t)(b * 64 + c) << 12) + qb0 + q0) = v2;
    s1 += __shfl_xor(s1, 1, 64);
    s2 += __shfl_xor(s2, 1, 64);
    s1 += __shfl_xor(s1, 2, 64);
    s2 += __shfl_xor(s2, 2, 64);
    s1 += __shfl_xor(s1, 4, 64);
    s2 += __shfl_xor(s2, 4, 64);
    if ((tid & 7) == 0) {
      atomicAdd(&gs1[c], s1);
      atomicAdd(&gs2[c], s2);
    }
  }
}

// ---------------------------------------------------------------------------
// apply: BN(scale/shift from gs1/gs2) + residual.
// ---------------------------------------------------------------------------
__global__ __launch_bounds__(256, 2) void pam_apply(
    const float* __restrict__ y0, const float* __restrict__ x,
    const float* __restrict__ gs1, const float* __restrict__ gs2,
    const float* __restrict__ bnw, const float* __restrict__ bnb,
    float* __restrict__ out)
{
  const int i = (blockIdx.x * 256 + threadIdx.x) << 2;   // 4 elems/thread
  const int c = (i >> 12) & 63;
  const float inv_n = 1.f / 16384.f;
  const float mean = gs1[c] * inv_n;
  const float var = fmaxf(gs2[c] * inv_n - mean * mean, 0.f);
  const float sc = bnw[c] * rsqrtf(var + 1e-5f);
  const float sh = bnb[c] - mean * sc;
  const float4 y = *(const float4*)(y0 + i);
  const float4 xv = *(const float4*)(x + i);
  float4 r;
  r.x = y.x * sc + sh + xv.x;
  r.y = y.y * sc + sh + xv.y;
  r.z = y.z * sc + sh + xv.z;
  r.w = y.w * sc + sh + xv.w;
  *(float4*)(out + i) = r;
}

// ---------------------------------------------------------------------------
extern "C" void kernel_launch(void* const* d_in, const int* in_sizes, int n_in,
                              void* d_out, int out_size, void* d_ws, size_t ws_size,
                              hipStream_t stream)
{
  (void)in_sizes; (void)n_in; (void)out_size; (void)ws_size;
  const float* x   = (const float*)d_in[0];
  const float* qw  = (const float*)d_in[1];
  const float* kw  = (const float*)d_in[2];
  const float* vw  = (const float*)d_in[3];
  const float* vb  = (const float*)d_in[4];
  const float* gam = (const float*)d_in[5];
  const float* bnw = (const float*)d_in[6];
  const float* bnb = (const float*)d_in[7];

  char* ws = (char*)d_ws;
  f16*   qa  = (f16*)(ws);
  f16*   ka2 = (f16*)(ws + (2u << 20));
  f16*   va3 = (f16*)(ws + (4u << 20));
  float* y0  = (float*)(ws + (6u << 20));
  float* gs1 = (float*)(ws + (10u << 20));          // 64 floats
  float* gs2 = (float*)(ws + (10u << 20) + 256);    // 64 floats (contiguous)

  pam_pre  <<<1024, 256, 0, stream>>>(x, qw, kw, vw, vb, qa, ka2, va3, gs1);
  pam_attn <<<1024, 512, 0, stream>>>(qa, ka2, va3, gam, y0, gs1, gs2);
  pam_apply<<<1024, 256, 0, stream>>>(y0, x, gs1, gs2, bnw, bnb, (float*)d_out);
}

// Round 13
// 146.488 us; speedup vs baseline: 1.2633x; 1.2633x over previous
//
#include <hip/hip_runtime.h>
#include <stdint.h>

using f16 = _Float16;

typedef _Float16 f16x8 __attribute__((ext_vector_type(8)));
typedef _Float16 f16x4 __attribute__((ext_vector_type(4)));
typedef float f32x4 __attribute__((ext_vector_type(4)));

#define LOG2E 1.44269504088896340736f

__device__ __forceinline__ f16 f2h(float f) { return (f16)f; }  // RNE

#if __has_builtin(__builtin_amdgcn_exp2f)
__device__ __forceinline__ float fexp2(float x) { return __builtin_amdgcn_exp2f(x); }
#else
__device__ __forceinline__ float fexp2(float x) { return exp2f(x); }
#endif

typedef __attribute__((address_space(1))) const uint32_t gu32;
typedef __attribute__((address_space(3))) uint32_t lu32;

__device__ __forceinline__ void dma16(const void* g, void* l) {
  // global->LDS DMA, 16 B/lane. Global source is PER-LANE (caller includes
  // lane*16B); LDS dest is wave-uniform base + lane*16 auto-stride.
  __builtin_amdgcn_global_load_lds((gu32*)g, (lu32*)l, 16, 0, 0);
}

__device__ __forceinline__ f16x8 cvt8(const float* p) {
  const float4 a = *(const float4*)p;
  const float4 b = *(const float4*)(p + 4);
  f16x8 r;
  r[0] = (f16)a.x; r[1] = (f16)a.y; r[2] = (f16)a.z; r[3] = (f16)a.w;
  r[4] = (f16)b.x; r[5] = (f16)b.y; r[6] = (f16)b.z; r[7] = (f16)b.w;
  return r;
}

// B=4, C=64, N=4096.  Global in/out FP32; internal tensor-core path FP16.
// ws layout (bytes):
//   0     qa  f16 [4][4096][64]      (2 MB)  q*log2e, position-major
//   2 MB  ka2 f16 [4][8][4096][8]    (2 MB)  K: [b][c8][key'][8c], key' = key
//                                            ^ ((key>>3&1)<<2 | (key>>4&1))
//   4 MB  va3 f16 [4][512][64][8]    (2 MB)  V key-chunked: [b][k8][c][8k]
//   6 MB  y0  f32 [4][64][4096]      (4 MB)  gamma*attn_out, pre-BN
//   10 MB stats: gs1[64] | gs2[64]   (zeroed by pre block 0)

// ---------------------------------------------------------------------------
// pre v3 (r7 verbatim): 1024 blocks x 256 thr, 16-pos tiles, vectorized I/O.
// ---------------------------------------------------------------------------
__global__ __launch_bounds__(256, 2) void pam_pre(
    const float* __restrict__ x, const float* __restrict__ qw,
    const float* __restrict__ kw, const float* __restrict__ vw,
    const float* __restrict__ vb,
    f16* __restrict__ qa, f16* __restrict__ ka2, f16* __restrict__ va3,
    float* __restrict__ gz)
{
  __shared__ alignas(16) f16 xt[16 * 72];   // xt[n][c] f16, row stride 72
  const int tid = threadIdx.x;
  const int b = blockIdx.x >> 8;
  const int n0 = (blockIdx.x & 255) << 4;
  const int lane = tid & 63;
  const int wv = tid >> 6;
  const int quad = lane >> 4, l15 = lane & 15;

  if (blockIdx.x == 0 && tid < 128) gz[tid] = 0.f;   // gs1|gs2 zero-init

  // stage x[b][c][n0:+16] (fp32) transposed into xt[n][c] (f16)
  {
    const int c = tid >> 2;
    const int j0 = (tid & 3) << 2;
    const float4 v0 = *(const float4*)(x + ((size_t)(b * 64 + c) << 12) + n0 + j0);
    xt[(j0 + 0) * 72 + c] = f2h(v0.x);
    xt[(j0 + 1) * 72 + c] = f2h(v0.y);
    xt[(j0 + 2) * 72 + c] = f2h(v0.z);
    xt[(j0 + 3) * 72 + c] = f2h(v0.w);
  }
  __syncthreads();

  // conv over channel axis (SAME, zero pad): 128 threads, 8 channels each
  if (tid < 128) {
    const float qw0 = qw[0], qw1 = qw[1], qw2 = qw[2];
    const float kw0 = kw[0], kw1 = kw[1], kw2 = kw[2];
    const int n = tid >> 3;            // 0..15
    const int c8 = tid & 7;            // 0..7
    const f16x8 v0 = *(const f16x8*)&xt[n * 72 + c8 * 8];
    const float lm = (c8 > 0) ? (float)xt[n * 72 + c8 * 8 - 1] : 0.f;
    const float rp = (c8 < 7) ? (float)xt[n * 72 + c8 * 8 + 8] : 0.f;
    f16x8 qv8, kv8;
#pragma unroll
    for (int j = 0; j < 8; ++j) {
      const float xm = (j == 0) ? lm : (float)v0[j - 1];
      const float x0 = (float)v0[j];
      const float xp = (j == 7) ? rp : (float)v0[j + 1];
      qv8[j] = f2h((qw0 * xm + qw1 * x0 + qw2 * xp) * LOG2E);  // log2-domain
      kv8[j] = f2h(kw0 * xm + kw1 * x0 + kw2 * xp);
    }
    const int nn = n0 + n;
    *(f16x8*)(qa + ((size_t)((b << 12) + nn) << 6) + c8 * 8) = qv8;
    // bank-fix storage permutation: flip key bits [2],[0] by bits [3],[4]
    const int np = nn ^ ((((nn >> 3) & 1) << 2) | ((nn >> 4) & 1));
    *(f16x8*)(ka2 + (((size_t)(b * 8 + c8)) << 15) + (np << 3)) = kv8;
  }

  // v^T[n][co] via mfma; wave wv -> co columns [16wv,+16)
  {
    const f16x8 a0 = *(const f16x8*)&xt[l15 * 72 + quad * 8];
    const f16x8 a1 = *(const f16x8*)&xt[l15 * 72 + quad * 8 + 32];
    const int co = wv * 16 + l15;
    const f16x8 b0 = cvt8(vw + co * 64 + quad * 8);
    const f16x8 b1 = cvt8(vw + co * 64 + quad * 8 + 32);
    f32x4 z = {0.f, 0.f, 0.f, 0.f};
    z = __builtin_amdgcn_mfma_f32_16x16x32_f16(a0, b0, z, 0, 0, 0);
    z = __builtin_amdgcn_mfma_f32_16x16x32_f16(a1, b1, z, 0, 0, 0);
    const float vbv = vb[co];
    f16x4 pv;
#pragma unroll
    for (int r = 0; r < 4; ++r) pv[r] = f2h(z[r] + vbv);
    const int nb = n0 + quad * 4;      // 4 consecutive n per thread
    *(f16x4*)(va3 + (((size_t)(b * 512 + (nb >> 3))) << 9)
              + (co << 3) + (nb & 7)) = pv;
  }
}

// ---------------------------------------------------------------------------
// attention v27 = r7 skeleton with DUAL-STREAM per-wave ILP (the one untested
// axis after r10/r11/r12 falsified DMA-drain, barriers, conflicts and TLP):
//  - two independent online-softmax streams per wave: stream A owns EVEN
//    128-key tiles, stream B ODD tiles, each with private (m, lp, o[4]);
//    merged at the end as 8 slices (ks x stream).  The ~800-cy serial chain
//    (QK^T -> cross-lane max -> exp -> PV) now has a second independent
//    chain to interleave with -> issue density ~2x at unchanged wave count.
//  - 16 iterations, K quad-buffered (4 x 16 KB).  Per iter: DMA(next pair)
//    at top -> V(A),V(B) -> QK^T A,B -> softmax A,B -> PV A,B -> barrier.
//    In-order vmcnt: PV A's V-wait retires the DMA (~800 cy cover), so the
//    end-of-iter __syncthreads drains NOTHING -- pure reconvergence, and
//    only 16 of them (was 32).
//  - streams combine in-register before the ldsO atomicAdd (atomic count
//    unchanged vs r7).  All r7 ingredients kept: XOR K-perm gather (S^T regs
//    land in PV B-frag k-order, zero-shuffle P), O^T PV via 16x16x32,
//    V global->VGPR, lane-local defer-max, 2 blocks/CU (LDS ~75 KB).
// ---------------------------------------------------------------------------
__global__ __launch_bounds__(512, 4) void pam_attn(
    const f16* __restrict__ qa, const f16* __restrict__ ka2,
    const f16* __restrict__ va3, const float* __restrict__ gam,
    float* __restrict__ y0, float* __restrict__ gs1, float* __restrict__ gs2)
{
  __shared__ alignas(16) f16 kbuf[4][8192];   // [c8][128key'][8c], 16 KB/slot
  __shared__ float ldsO[32 * 65];             // [q][c], pad 65
  __shared__ float ldsM[8][32], ldsL[8][32], ldsMg[32], ldsInv[32];

  const int tid = threadIdx.x;
  const int wv = tid >> 6, lane = tid & 63;
  const int quad = lane >> 4, l15 = lane & 15;
  const int ks = wv & 3, qh = wv >> 2;
  const int b = blockIdx.x & 3;
  const int qb = blockIdx.x >> 2;          // 0..127
  const int qb0 = qb << 5;

  for (int i = tid; i < 32 * 65; i += 512) ldsO[i] = 0.f;

  const int bn = b << 12;
  // Q fragments (B-operand: col=l15=q, k=quad*8+j over channels)
  f16x8 bq0, bq1;
  {
    const int q = qb0 + qh * 16 + l15;
    const f16* qp = qa + ((size_t)(bn + q) << 6) + quad * 8;
    bq0 = *(const f16x8*)qp;
    bq1 = *(const f16x8*)(qp + 32);
  }

  // K staging base (PER-LANE source: + lane*8 f16 = 16 B/lane).
  const f16* kg0 = ka2 + (((size_t)(b * 8 + wv)) << 15) + (lane << 3);
  // V per-lane global base: va3[b][k8 = 16*g + ks*4 + quad][c][8k], +l15*8
  const f16* vgp = va3 + ((size_t)b << 18) + ((ks * 4 + quad) << 9) + (l15 << 3);

  f32x4 oA[4] = {}, oB[4] = {};    // O^T per stream: col=l15=q
  float mA = -1e30f, lpA = 0.f, mB = -1e30f, lpB = 0.f;

  // prologue: stage pair 0 (logical tiles 0,1) into slots 0,1
  {
    const int g0 = (qb & 15) << 1, g1 = g0 | 1;
    dma16(kg0 + ((size_t)g0 << 10),       kbuf[0] + (wv << 10));
    dma16(kg0 + ((size_t)g0 << 10) + 512, kbuf[0] + (wv << 10) + 512);
    dma16(kg0 + ((size_t)g1 << 10),       kbuf[1] + (wv << 10));
    dma16(kg0 + ((size_t)g1 << 10) + 512, kbuf[1] + (wv << 10) + 512);
  }
  __syncthreads();

  // K gather with both-sides XOR: S^T reg r of quad holds key
  // ks*32 + quad*8 + t*4 + r == PV k-order (zero-shuffle P).
  const int u = l15 >> 2;
  const int xmsk = ((u & 1) << 2) | (u >> 1);
  const int pos0 = (ks << 5) + (u << 3) + (l15 & 3);
  const int koff0 = (pos0 ^ xmsk) << 3;
  const int koff1 = koff0 ^ 32;                // (pos0+4)^mask, same mask

#pragma unroll 1
  for (int p = 0; p < 16; ++p) {
    const int sA = (2 * p) & 3, sB = (2 * p + 1) & 3;
    const int pr = (p + qb) & 15;            // L2-spread pair rotation
    const int gA = pr << 1, gB = gA | 1;

    // prefetch DMA for next pair (oldest in queue; retired by PV A's V-wait)
    if (p < 15) {
      const int prn = (p + 1 + qb) & 15;
      const int gnA = prn << 1, gnB = gnA | 1;
      f16* kdA = kbuf[(2 * p + 2) & 3] + (wv << 10);
      f16* kdB = kbuf[(2 * p + 3) & 3] + (wv << 10);
      dma16(kg0 + ((size_t)gnA << 10),       kdA);
      dma16(kg0 + ((size_t)gnA << 10) + 512, kdA + 512);
      dma16(kg0 + ((size_t)gnB << 10),       kdB);
      dma16(kg0 + ((size_t)gnB << 10) + 512, kdB + 512);
    }

    // V fragments for both tiles (issued after DMA: in-order retirement
    // means PV's V-waits retire the DMA first, with QK^T+softmax cover)
    const f16* vtA = vgp + ((size_t)gA << 13);
    const f16x8 avA0 = *(const f16x8*)(vtA);
    const f16x8 avA1 = *(const f16x8*)(vtA + 128);
    const f16x8 avA2 = *(const f16x8*)(vtA + 256);
    const f16x8 avA3 = *(const f16x8*)(vtA + 384);
    const f16* vtB = vgp + ((size_t)gB << 13);
    const f16x8 avB0 = *(const f16x8*)(vtB);
    const f16x8 avB1 = *(const f16x8*)(vtB + 128);
    const f16x8 avB2 = *(const f16x8*)(vtB + 256);
    const f16x8 avB3 = *(const f16x8*)(vtB + 384);

    // QK^T stream A (tile gA from slot sA)
    f32x4 zA0, zA1;
    {
      const f16* kc = kbuf[sA];
      const f16x8 ak00 = *(const f16x8*)(kc + (quad << 10) + koff0);
      const f16x8 ak01 = *(const f16x8*)(kc + ((4 + quad) << 10) + koff0);
      const f16x8 ak10 = *(const f16x8*)(kc + (quad << 10) + koff1);
      const f16x8 ak11 = *(const f16x8*)(kc + ((4 + quad) << 10) + koff1);
      f32x4 z = {0.f, 0.f, 0.f, 0.f};
      z = __builtin_amdgcn_mfma_f32_16x16x32_f16(ak00, bq0, z, 0, 0, 0);
      zA0 = __builtin_amdgcn_mfma_f32_16x16x32_f16(ak01, bq1, z, 0, 0, 0);
      f32x4 y = {0.f, 0.f, 0.f, 0.f};
      y = __builtin_amdgcn_mfma_f32_16x16x32_f16(ak10, bq0, y, 0, 0, 0);
      zA1 = __builtin_amdgcn_mfma_f32_16x16x32_f16(ak11, bq1, y, 0, 0, 0);
    }
    // QK^T stream B (tile gB from slot sB) -- independent chain
    f32x4 zB0, zB1;
    {
      const f16* kc = kbuf[sB];
      const f16x8 ak00 = *(const f16x8*)(kc + (quad << 10) + koff0);
      const f16x8 ak01 = *(const f16x8*)(kc + ((4 + quad) << 10) + koff0);
      const f16x8 ak10 = *(const f16x8*)(kc + (quad << 10) + koff1);
      const f16x8 ak11 = *(const f16x8*)(kc + ((4 + quad) << 10) + koff1);
      f32x4 z = {0.f, 0.f, 0.f, 0.f};
      z = __builtin_amdgcn_mfma_f32_16x16x32_f16(ak00, bq0, z, 0, 0, 0);
      zB0 = __builtin_amdgcn_mfma_f32_16x16x32_f16(ak01, bq1, z, 0, 0, 0);
      f32x4 y = {0.f, 0.f, 0.f, 0.f};
      y = __builtin_amdgcn_mfma_f32_16x16x32_f16(ak10, bq0, y, 0, 0, 0);
      zB1 = __builtin_amdgcn_mfma_f32_16x16x32_f16(ak11, bq1, y, 0, 0, 0);
    }

    // softmax stream A (lane-local, defer-max THR=8)
    f16x8 paA;
    {
      float tmax = fmaxf(fmaxf(fmaxf(zA0[0], zA0[1]), fmaxf(zA0[2], zA0[3])),
                         fmaxf(fmaxf(zA1[0], zA1[1]), fmaxf(zA1[2], zA1[3])));
      tmax = fmaxf(tmax, __shfl_xor(tmax, 16, 64));
      tmax = fmaxf(tmax, __shfl_xor(tmax, 32, 64));
      const bool need = !__all(tmax <= mA + 8.f);
      const float mn = need ? fmaxf(mA, tmax) : mA;
      const float p0 = fexp2(zA0[0] - mn), p1 = fexp2(zA0[1] - mn);
      const float p2 = fexp2(zA0[2] - mn), p3 = fexp2(zA0[3] - mn);
      const float p4 = fexp2(zA1[0] - mn), p5 = fexp2(zA1[1] - mn);
      const float p6 = fexp2(zA1[2] - mn), p7 = fexp2(zA1[3] - mn);
      const float ts = ((p0 + p1) + (p2 + p3)) + ((p4 + p5) + (p6 + p7));
      paA[0] = f2h(p0); paA[1] = f2h(p1); paA[2] = f2h(p2); paA[3] = f2h(p3);
      paA[4] = f2h(p4); paA[5] = f2h(p5); paA[6] = f2h(p6); paA[7] = f2h(p7);
      if (need) {
        const float al = fexp2(mA - mn);
        lpA = lpA * al + ts;
        mA = mn;
#pragma unroll
        for (int ct = 0; ct < 4; ++ct)
          for (int r = 0; r < 4; ++r) oA[ct][r] *= al;
      } else {
        lpA += ts;
      }
    }
    // softmax stream B -- independent chain
    f16x8 paB;
    {
      float tmax = fmaxf(fmaxf(fmaxf(zB0[0], zB0[1]), fmaxf(zB0[2], zB0[3])),
                         fmaxf(fmaxf(zB1[0], zB1[1]), fmaxf(zB1[2], zB1[3])));
      tmax = fmaxf(tmax, __shfl_xor(tmax, 16, 64));
      tmax = fmaxf(tmax, __shfl_xor(tmax, 32, 64));
      const bool need = !__all(tmax <= mB + 8.f);
      const float mn = need ? fmaxf(mB, tmax) : mB;
      const float p0 = fexp2(zB0[0] - mn), p1 = fexp2(zB0[1] - mn);
      const float p2 = fexp2(zB0[2] - mn), p3 = fexp2(zB0[3] - mn);
      const float p4 = fexp2(zB1[0] - mn), p5 = fexp2(zB1[1] - mn);
      const float p6 = fexp2(zB1[2] - mn), p7 = fexp2(zB1[3] - mn);
      const float ts = ((p0 + p1) + (p2 + p3)) + ((p4 + p5) + (p6 + p7));
      paB[0] = f2h(p0); paB[1] = f2h(p1); paB[2] = f2h(p2); paB[3] = f2h(p3);
      paB[4] = f2h(p4); paB[5] = f2h(p5); paB[6] = f2h(p6); paB[7] = f2h(p7);
      if (need) {
        const float al = fexp2(mB - mn);
        lpB = lpB * al + ts;
        mB = mn;
#pragma unroll
        for (int ct = 0; ct < 4; ++ct)
          for (int r = 0; r < 4; ++r) oB[ct][r] *= al;
      } else {
        lpB += ts;
      }
    }

    // PV A (V-wait here retires the DMA, ~800 cy after issue), then PV B
    oA[0] = __builtin_amdgcn_mfma_f32_16x16x32_f16(avA0, paA, oA[0], 0, 0, 0);
    oA[1] = __builtin_amdgcn_mfma_f32_16x16x32_f16(avA1, paA, oA[1], 0, 0, 0);
    oA[2] = __builtin_amdgcn_mfma_f32_16x16x32_f16(avA2, paA, oA[2], 0, 0, 0);
    oA[3] = __builtin_amdgcn_mfma_f32_16x16x32_f16(avA3, paA, oA[3], 0, 0, 0);
    oB[0] = __builtin_amdgcn_mfma_f32_16x16x32_f16(avB0, paB, oB[0], 0, 0, 0);
    oB[1] = __builtin_amdgcn_mfma_f32_16x16x32_f16(avB1, paB, oB[1], 0, 0, 0);
    oB[2] = __builtin_amdgcn_mfma_f32_16x16x32_f16(avB2, paB, oB[2], 0, 0, 0);
    oB[3] = __builtin_amdgcn_mfma_f32_16x16x32_f16(avB3, paB, oB[3], 0, 0, 0);

    __syncthreads();   // nothing outstanding: pure reconvergence (16 total)
  }

  // publish per-wave online state: slices (ks*2 | stream)
  lpA += __shfl_xor(lpA, 16, 64);
  lpA += __shfl_xor(lpA, 32, 64);
  lpB += __shfl_xor(lpB, 16, 64);
  lpB += __shfl_xor(lpB, 32, 64);
  if (quad == 0) {
    const int q = qh * 16 + l15;
    ldsM[ks * 2][q] = mA;  ldsL[ks * 2][q] = lpA;
    ldsM[ks * 2 + 1][q] = mB;  ldsL[ks * 2 + 1][q] = lpB;
  }
  __syncthreads();

  // per-query global max + denom (8 slices)
  if (tid < 32) {
    float M = ldsM[0][tid];
#pragma unroll
    for (int k = 1; k < 8; ++k) M = fmaxf(M, ldsM[k][tid]);
    float lt = 0.f;
#pragma unroll
    for (int k = 0; k < 8; ++k) lt += ldsL[k][tid] * fexp2(ldsM[k][tid] - M);
    ldsMg[tid] = M;
    ldsInv[tid] = 1.f / lt;
  }
  __syncthreads();

  // m-aware merge: combine streams in-register, one atomicAdd per element
  {
    const int q = qh * 16 + l15;
    const float scA = fexp2(mA - ldsMg[q]);
    const float scB = fexp2(mB - ldsMg[q]);
#pragma unroll
    for (int ct = 0; ct < 4; ++ct)
      for (int r = 0; r < 4; ++r)
        atomicAdd(&ldsO[q * 65 + ct * 16 + quad * 4 + r],
                  oA[ct][r] * scA + oB[ct][r] * scB);
  }
  __syncthreads();

  // epilogue: y0[b][c][n] = gamma * O / l ; BN partial sums
  const float g = gam[0];
  {
    const int c = tid >> 3;              // 0..63
    const int q0 = (tid & 7) << 2;       // 0..28
    float4 v4;
    float* vp = &v4.x;
    float s1 = 0.f, s2 = 0.f;
    for (int r = 0; r < 4; ++r) {
      const float val = g * ldsO[(q0 + r) * 65 + c] * ldsInv[q0 + r];
      vp[r] = val; s1 += val; s2 += val * val;
    }
    *(float4*)(y0 + ((size_t)(b * 64 + c) << 12) + qb0 + q0) = v4;
    s1 += __shfl_xor(s1, 1, 64);
    s2 += __shfl_xor(s2, 1, 64);
    s1 += __shfl_xor(s1, 2, 64);
    s2 += __shfl_xor(s2, 2, 64);
    s1 += __shfl_xor(s1, 4, 64);
    s2 += __shfl_xor(s2, 4, 64);
    if ((tid & 7) == 0) {
      atomicAdd(&gs1[c], s1);
      atomicAdd(&gs2[c], s2);
    }
  }
}

// ---------------------------------------------------------------------------
// apply: BN(scale/shift from gs1/gs2) + residual.
// ---------------------------------------------------------------------------
__global__ __launch_bounds__(256, 2) void pam_apply(
    const float* __restrict__ y0, const float* __restrict__ x,
    const float* __restrict__ gs1, const float* __restrict__ gs2,
    const float* __restrict__ bnw, const float* __restrict__ bnb,
    float* __restrict__ out)
{
  const int i = (blockIdx.x * 256 + threadIdx.x) << 2;   // 4 elems/thread
  const int c = (i >> 12) & 63;
  const float inv_n = 1.f / 16384.f;
  const float mean = gs1[c] * inv_n;
  const float var = fmaxf(gs2[c] * inv_n - mean * mean, 0.f);
  const float sc = bnw[c] * rsqrtf(var + 1e-5f);
  const float sh = bnb[c] - mean * sc;
  const float4 y = *(const float4*)(y0 + i);
  const float4 xv = *(const float4*)(x + i);
  float4 r;
  r.x = y.x * sc + sh + xv.x;
  r.y = y.y * sc + sh + xv.y;
  r.z = y.z * sc + sh + xv.z;
  r.w = y.w * sc + sh + xv.w;
  *(float4*)(out + i) = r;
}

// ---------------------------------------------------------------------------
extern "C" void kernel_launch(void* const* d_in, const int* in_sizes, int n_in,
                              void* d_out, int out_size, void* d_ws, size_t ws_size,
                              hipStream_t stream)
{
  (void)in_sizes; (void)n_in; (void)out_size; (void)ws_size;
  const float* x   = (const float*)d_in[0];
  const float* qw  = (const float*)d_in[1];
  const float* kw  = (const float*)d_in[2];
  const float* vw  = (const float*)d_in[3];
  const float* vb  = (const float*)d_in[4];
  const float* gam = (const float*)d_in[5];
  const float* bnw = (const float*)d_in[6];
  const float* bnb = (const float*)d_in[7];

  char* ws = (char*)d_ws;
  f16*   qa  = (f16*)(ws);
  f16*   ka2 = (f16*)(ws + (2u << 20));
  f16*   va3 = (f16*)(ws + (4u << 20));
  float* y0  = (float*)(ws + (6u << 20));
  float* gs1 = (float*)(ws + (10u << 20));          // 64 floats
  float* gs2 = (float*)(ws + (10u << 20) + 256);    // 64 floats (contiguous)

  pam_pre  <<<1024, 256, 0, stream>>>(x, qw, kw, vw, vb, qa, ka2, va3, gs1);
  pam_attn <<<512, 512, 0, stream>>>(qa, ka2, va3, gam, y0, gs1, gs2);
  pam_apply<<<1024, 256, 0, stream>>>(y0, x, gs1, gs2, bnw, bnb, (float*)d_out);
}